// Round 13
// baseline (146.722 us; speedup 1.0000x reference)
//
#include <hip/hip_runtime.h>
#include <hip/hip_bf16.h>

#define NB 128
#define LL 512
#define DD 512

typedef __attribute__((ext_vector_type(4))) float  f32x4;
typedef __attribute__((ext_vector_type(8))) short  s16x8;

#define AS1 __attribute__((address_space(1)))
#define AS3 __attribute__((address_space(3)))

__device__ __forceinline__ short f2bf(float f) {
    __hip_bfloat16 h = __float2bfloat16(f);
    return *reinterpret_cast<short*>(&h);
}

// monotone float<->uint mapping so atomicMax(uint) == float max
__device__ __forceinline__ unsigned fmap(float f) {
    unsigned u = __float_as_uint(f);
    return (u & 0x80000000u) ? ~u : (u | 0x80000000u);
}
__device__ __forceinline__ float funmap(unsigned u) {
    unsigned b = (u & 0x80000000u) ? (u ^ 0x80000000u) : ~u;
    return __uint_as_float(b);
}

__device__ __forceinline__ void gl16(const void* g, void* l) {
    __builtin_amdgcn_global_load_lds((const AS1 unsigned int*)g,
                                     (AS3 unsigned int*)l, 16, 0, 0);
}

// Pass 1: normalize fp32 rows -> bf16. 8 rows per wave, ALL 16 dwordx4 loads
// forced in flight simultaneously (the asm consumes every loaded value, so
// the compiler cannot sink loads to their uses -- R11 showed VGPR=32 load
// sinking capped the kernel at 2.5 TB/s). Also zeroes the max buffers.
// Grid: 4096 blocks x 4 waves x 8 rows = 131072 = 2*NB*LL rows, exact.
// (R12 bug: 2048 blocks covered only half the rows.)
__global__ __launch_bounds__(256) void normalize_fast(
        const float* __restrict__ x1, const float* __restrict__ x2,
        short* __restrict__ n1, short* __restrict__ n2,
        unsigned* __restrict__ maxbuf) {
    int tid = threadIdx.x;
    int gid = blockIdx.x * 256 + tid;
    if (gid < 2 * NB * LL) maxbuf[gid] = 0u;   // 0 < fmap of any real value

    int gw   = blockIdx.x * 4 + (tid >> 6);    // 16384 waves total
    int lane = tid & 63;
    int r0   = gw * 8;                         // 8 rows per wave, exact cover

    f32x4 v[8][2];
    #pragma unroll
    for (int i = 0; i < 8; ++i) {
        int row = r0 + i;
        const float* x = (row < NB * LL)
            ? x1 + (size_t)row * DD
            : x2 + (size_t)(row - NB * LL) * DD;
        const f32x4* p = reinterpret_cast<const f32x4*>(x);
        v[i][0] = p[2 * lane];
        v[i][1] = p[2 * lane + 1];
    }
    // one ordering point: all 16 loads issued, one vmcnt wait
    asm volatile("" ::
        "v"(v[0][0]), "v"(v[0][1]), "v"(v[1][0]), "v"(v[1][1]),
        "v"(v[2][0]), "v"(v[2][1]), "v"(v[3][0]), "v"(v[3][1]),
        "v"(v[4][0]), "v"(v[4][1]), "v"(v[5][0]), "v"(v[5][1]),
        "v"(v[6][0]), "v"(v[6][1]), "v"(v[7][0]), "v"(v[7][1]));

    float ss[8];
    #pragma unroll
    for (int i = 0; i < 8; ++i) {
        f32x4 a = v[i][0], c = v[i][1];
        ss[i] = a.x*a.x + a.y*a.y + a.z*a.z + a.w*a.w
              + c.x*c.x + c.y*c.y + c.z*c.z + c.w*c.w;
    }
    // 8 independent butterfly chains, interleaved for ILP
    #pragma unroll
    for (int off = 32; off >= 1; off >>= 1) {
        #pragma unroll
        for (int i = 0; i < 8; ++i)
            ss[i] += __shfl_xor(ss[i], off, 64);
    }
    #pragma unroll
    for (int i = 0; i < 8; ++i) {
        float s = 1.0f / fmaxf(sqrtf(ss[i]), 1e-8f);
        f32x4 a = v[i][0], c = v[i][1];
        s16x8 o;
        o[0] = f2bf(a.x * s); o[1] = f2bf(a.y * s);
        o[2] = f2bf(a.z * s); o[3] = f2bf(a.w * s);
        o[4] = f2bf(c.x * s); o[5] = f2bf(c.y * s);
        o[6] = f2bf(c.z * s); o[7] = f2bf(c.w * s);
        int row = r0 + i;
        short* n = (row < NB * LL)
            ? n1 + (size_t)row * DD
            : n2 + (size_t)(row - NB * LL) * DD;
        reinterpret_cast<s16x8*>(n)[lane] = o;
    }
}

// stage 128 rows x 64 k (bf16) into a 16 KB LDS buffer, linear dest +
// inverse-swizzled global source: logical byte = linear ^ ((row&7)<<4)
__device__ __forceinline__ void stage128x64(
        const short* __restrict__ src, int k0, char* ldsb, int w, int lane) {
    #pragma unroll
    for (int j = 0; j < 4; ++j) {
        int L   = (j * 4 + w) * 1024 + lane * 16;   // linear LDS byte offset
        int row = L >> 7;                           // 128 B per row
        int kg  = ((L >> 4) & 7) ^ (row & 7);       // inverse swizzle on source
        const short* g = src + (size_t)row * DD + k0 + kg * 8;
        gl16(g, ldsb + (j * 4 + w) * 1024);         // HW adds lane*16
    }
}

// Pass 2: 128x128x512 bf16 GEMM + masked row/col max (R2-proven kernel).
__global__ __launch_bounds__(256) void simgemm_kernel(
        const short* __restrict__ n1, const short* __restrict__ n2,
        const int* __restrict__ mask1, const int* __restrict__ mask2,
        unsigned* __restrict__ rowmax_u, unsigned* __restrict__ colmax_u) {
    __shared__ __align__(16) char lds[65536];
    // layout: A0 @0, B0 @16384, A1 @32768, B1 @49152

    int bid = blockIdx.x;
    int lid = (bid & 7) * 256 + (bid >> 3);   // XCD-chunked bijective swizzle (nwg=2048)
    int b   = lid >> 4;
    int tr  = (lid >> 2) & 3;
    int tc  = lid & 3;

    int tid  = threadIdx.x;
    int lane = tid & 63;
    int w    = tid >> 6;
    int wr = w >> 1, wc = w & 1;
    int l15 = lane & 15, lhi = lane >> 4;

    const short* Abase = n1 + ((size_t)b * LL + tr * 128) * DD;
    const short* Bbase = n2 + ((size_t)b * LL + tc * 128) * DD;

    f32x4 acc[4][4];
    #pragma unroll
    for (int fr = 0; fr < 4; ++fr)
        #pragma unroll
        for (int fc = 0; fc < 4; ++fc) {
            acc[fr][fc].x = 0.f; acc[fr][fc].y = 0.f;
            acc[fr][fc].z = 0.f; acc[fr][fc].w = 0.f;
        }

    // prologue: stage K-tile 0 into buffer 0
    stage128x64(Abase, 0, lds,         w, lane);
    stage128x64(Bbase, 0, lds + 16384, w, lane);
    __syncthreads();

    int cur = 0;
    for (int t = 0; t < 8; ++t) {
        // issue next-tile loads first so they fly under ds_read+MFMA
        if (t < 7) {
            char* nb = lds + (cur ^ 1) * 32768;
            stage128x64(Abase, (t + 1) * 64, nb,         w, lane);
            stage128x64(Bbase, (t + 1) * 64, nb + 16384, w, lane);
        }
        char* As = lds + cur * 32768;
        char* Bs = As + 16384;
        #pragma unroll
        for (int ks = 0; ks < 2; ++ks) {
            s16x8 af[4], bf[4];
            #pragma unroll
            for (int fr = 0; fr < 4; ++fr) {
                int row = wr * 64 + fr * 16 + l15;
                unsigned byte = (unsigned)(row * 128 + ks * 64 + lhi * 16)
                              ^ ((unsigned)(row & 7) << 4);
                af[fr] = *reinterpret_cast<const s16x8*>(As + byte);
            }
            #pragma unroll
            for (int fc = 0; fc < 4; ++fc) {
                int crow = wc * 64 + fc * 16 + l15;
                unsigned byte = (unsigned)(crow * 128 + ks * 64 + lhi * 16)
                              ^ ((unsigned)(crow & 7) << 4);
                bf[fc] = *reinterpret_cast<const s16x8*>(Bs + byte);
            }
            #pragma unroll
            for (int fr = 0; fr < 4; ++fr)
                #pragma unroll
                for (int fc = 0; fc < 4; ++fc)
                    acc[fr][fc] = __builtin_amdgcn_mfma_f32_16x16x32_bf16(
                        af[fr], bf[fc], acc[fr][fc], 0, 0, 0);
        }
        __syncthreads();   // drains vmcnt (stage done) + all reads of cur done
        cur ^= 1;
    }

    // ---- epilogue: masked row/col maxes ----
    int m2[4];
    #pragma unroll
    for (int fc = 0; fc < 4; ++fc)
        m2[fc] = mask2[b * LL + tc * 128 + wc * 64 + fc * 16 + l15];
    int m1[4][4];
    #pragma unroll
    for (int fr = 0; fr < 4; ++fr)
        #pragma unroll
        for (int r = 0; r < 4; ++r)
            m1[fr][r] = mask1[b * LL + tr * 128 + wr * 64 + fr * 16 + lhi * 4 + r];

    // row max: per (fr,r) max over this wave's 64 cols (mask2-gated)
    #pragma unroll
    for (int fr = 0; fr < 4; ++fr) {
        #pragma unroll
        for (int r = 0; r < 4; ++r) {
            float v = -INFINITY;
            #pragma unroll
            for (int fc = 0; fc < 4; ++fc)
                if (m2[fc]) v = fmaxf(v, acc[fr][fc][r]);
            v = fmaxf(v, __shfl_xor(v, 1, 64));
            v = fmaxf(v, __shfl_xor(v, 2, 64));
            v = fmaxf(v, __shfl_xor(v, 4, 64));
            v = fmaxf(v, __shfl_xor(v, 8, 64));
            if (l15 == 0)
                atomicMax(&rowmax_u[b * LL + tr * 128 + wr * 64 + fr * 16 + lhi * 4 + r],
                          fmap(v));
        }
    }
    // col max: per fc col, max over this wave's 64 rows (mask1-gated)
    #pragma unroll
    for (int fc = 0; fc < 4; ++fc) {
        float v = -INFINITY;
        #pragma unroll
        for (int fr = 0; fr < 4; ++fr)
            #pragma unroll
            for (int r = 0; r < 4; ++r)
                if (m1[fr][r]) v = fmaxf(v, acc[fr][fc][r]);
        v = fmaxf(v, __shfl_xor(v, 16, 64));
        v = fmaxf(v, __shfl_xor(v, 32, 64));
        if (lhi == 0)
            atomicMax(&colmax_u[b * LL + tc * 128 + wc * 64 + fc * 16 + l15], fmap(v));
    }
}

__global__ __launch_bounds__(64) void finalize_kernel(
        const unsigned* __restrict__ rowmax_u, const unsigned* __restrict__ colmax_u,
        const int* __restrict__ mask1, const int* __restrict__ mask2,
        float* __restrict__ out) {
    int b = blockIdx.x;
    int lane = threadIdx.x;
    float s1 = 0.f, c1 = 0.f, s2 = 0.f, c2 = 0.f;
    for (int i = lane; i < LL; i += 64) {
        if (mask1[b * LL + i]) { s1 += funmap(rowmax_u[b * LL + i]); c1 += 1.f; }
        if (mask2[b * LL + i]) { s2 += funmap(colmax_u[b * LL + i]); c2 += 1.f; }
    }
    #pragma unroll
    for (int off = 32; off >= 1; off >>= 1) {
        s1 += __shfl_xor(s1, off, 64);
        c1 += __shfl_xor(c1, off, 64);
        s2 += __shfl_xor(s2, off, 64);
        c2 += __shfl_xor(c2, off, 64);
    }
    if (lane == 0) out[b] = 0.5f * (s1 / c1 + s2 / c2);
}

extern "C" void kernel_launch(void* const* d_in, const int* in_sizes, int n_in,
                              void* d_out, int out_size, void* d_ws, size_t ws_size,
                              hipStream_t stream) {
    const float* x1    = (const float*)d_in[0];
    const int*   mask1 = (const int*)d_in[1];
    const float* x2    = (const float*)d_in[2];
    const int*   mask2 = (const int*)d_in[3];
    float* out = (float*)d_out;

    size_t nElem = (size_t)NB * LL * DD;   // 33.5 M
    short* n1 = (short*)d_ws;
    short* n2 = n1 + nElem;
    unsigned* rowmax_u = (unsigned*)(n2 + nElem);
    unsigned* colmax_u = rowmax_u + NB * LL;

    normalize_fast<<<4096, 256, 0, stream>>>(x1, x2, n1, n2, rowmax_u);
    simgemm_kernel<<<NB * 16, 256, 0, stream>>>(n1, n2, mask1, mask2,
                                                rowmax_u, colmax_u);
    finalize_kernel<<<NB, 64, 0, stream>>>(rowmax_u, colmax_u, mask1, mask2, out);
}